// Round 14
// baseline (707.578 us; speedup 1.0000x reference)
//
#include <hip/hip_runtime.h>
#include <hip/hip_bf16.h>

#define N_NODESC 50000
#define N_EDGESC 400000
#define N_GRAPHSC 250
#define DDIM 256
#define NCLS 10
#define BN_EPSF 1e-5f
#define MPAD 50048   // 391 * 128
#define NBLK_GEMM 391          // 17 * 23
#define NBLK_SCAN 196

typedef __attribute__((ext_vector_type(4))) float f32x4;
typedef __attribute__((ext_vector_type(8))) short bf16x8;
typedef __attribute__((ext_vector_type(8))) unsigned short u16x8;

__device__ __forceinline__ float bf2f(unsigned short h) {
    union { unsigned int u; float f; } c;
    c.u = ((unsigned int)h) << 16;
    return c.f;
}
__device__ __forceinline__ unsigned short f2bf(float f) {
    union { float f; unsigned int u; } c;
    c.f = f;
    unsigned int u = c.u;
    return (unsigned short)((u + 0x7FFFu + ((u >> 16) & 1u)) >> 16);
}

__device__ __forceinline__ void gld_lds16(const void* g, void* l) {
    __builtin_amdgcn_global_load_lds(
        (const __attribute__((address_space(1))) unsigned int*)g,
        (__attribute__((address_space(3))) unsigned int*)l, 16, 0, 0);
}

// ---------------- CSR build ----------------

__global__ void k_zero32(int* __restrict__ p, int n) {
    int i = blockIdx.x * blockDim.x + threadIdx.x;
    if (i < n) p[i] = 0;
}

__global__ void k_count(const int* __restrict__ dst, int* __restrict__ cnt) {
    int e = blockIdx.x * blockDim.x + threadIdx.x;
    if (e < N_EDGESC) atomicAdd(&cnt[dst[e]], 1);
}

__global__ __launch_bounds__(256) void k_scan1(const int* __restrict__ deg,
                                               int* __restrict__ rowstart,
                                               int* __restrict__ bsum) {
    __shared__ int sh[256];
    int tid = threadIdx.x;
    int i = blockIdx.x * 256 + tid;
    int v = (i < N_NODESC) ? deg[i] : 0;
    sh[tid] = v;
    __syncthreads();
    for (int off = 1; off < 256; off <<= 1) {
        int t = (tid >= off) ? sh[tid - off] : 0;
        __syncthreads();
        sh[tid] += t;
        __syncthreads();
    }
    if (i < N_NODESC) rowstart[i] = sh[tid] - v;
    if (tid == 255) bsum[blockIdx.x] = sh[255];
}

__global__ __launch_bounds__(256) void k_scan2(int* __restrict__ rowstart,
                                               const int* __restrict__ bsum) {
    __shared__ int sh[256];
    int tid = threadIdx.x;
    sh[tid] = (tid < NBLK_SCAN) ? bsum[tid] : 0;
    __syncthreads();
    for (int off = 1; off < 256; off <<= 1) {
        int t = (tid >= off) ? sh[tid - off] : 0;
        __syncthreads();
        sh[tid] += t;
        __syncthreads();
    }
    int i = blockIdx.x * 256 + tid;
    if (blockIdx.x > 0 && i < N_NODESC) rowstart[i] += sh[blockIdx.x - 1];
    if (i == 0) rowstart[N_NODESC] = N_EDGESC;
}

__global__ void k_fill(const int* __restrict__ src, const int* __restrict__ dst,
                       const int* __restrict__ rowstart, int* __restrict__ cur,
                       int* __restrict__ esrc) {
    int e = blockIdx.x * blockDim.x + threadIdx.x;
    if (e < N_EDGESC) {
        int d = dst[e];
        int pos = rowstart[d] + atomicAdd(&cur[d], 1);
        esrc[pos] = src[e];
    }
}

// ---------------- weight prep: W[k][n] f32 -> Wt[n][k] bf16, 10 matrices ----------------

__global__ __launch_bounds__(256) void k_wprep(const float* __restrict__ W1a,
                                               const float* __restrict__ W1b,
                                               const float* __restrict__ Ws1,
                                               const float* __restrict__ Ws2,
                                               unsigned short* __restrict__ Wt) {
    int i = blockIdx.x * blockDim.x + threadIdx.x;
    if (i >= 10 * 65536) return;
    int m = i >> 16;
    int r = i & 65535;
    int n = r >> 8;
    int k = r & 255;
    int l = m >> 1, wsel = m & 1;
    const float* src = (l == 0) ? (wsel ? W1b : W1a)
                                : (wsel ? Ws2 + (size_t)(l - 1) * 65536
                                        : Ws1 + (size_t)(l - 1) * 65536);
    Wt[i] = f2bf(src[(size_t)k * 256 + n]);
}

// x fp32 -> bf16
__global__ __launch_bounds__(256) void k_xbf(const float* __restrict__ X,
                                             unsigned short* __restrict__ Y) {
    int i = blockIdx.x * 256 + threadIdx.x;
    if (i < N_NODESC * 64) {
        float4 v = ((const float4*)X)[i];
        ushort4 o;
        o.x = f2bf(v.x); o.y = f2bf(v.y); o.z = f2bf(v.z); o.w = f2bf(v.w);
        ((ushort4*)Y)[i] = o;
    }
}

// ---------------- mean aggregation + (optional) previous layer's BN ----------------
// BN affine commutes with mean-agg: out = sc*(x + mean_src) + tt*(deg>0?2:1).
// One node per half-wave (32 lanes x 16B = 512B row), unroll x4.

__global__ __launch_bounds__(256) void k_agg_bf(const unsigned short* __restrict__ X,
                                                const int* __restrict__ esrc,
                                                const int* __restrict__ rowstart,
                                                const float* __restrict__ stat,
                                                const float* __restrict__ gamma,
                                                const float* __restrict__ beta,
                                                unsigned short* __restrict__ Hout) {
    int node = blockIdx.x * 8 + (threadIdx.x >> 5);
    if (node >= N_NODESC) return;
    int lane = threadIdx.x & 31;
    int d0 = lane * 8;
    float sc[8], tt[8];
    if (stat) {
        const float invN = 1.0f / (float)N_NODESC;
#pragma unroll
        for (int q = 0; q < 8; q++) {
            float mu = stat[d0 + q] * invN;
            float var = stat[256 + d0 + q] * invN - mu * mu;
            float s = gamma[d0 + q] * rsqrtf(var + BN_EPSF);
            sc[q] = s;
            tt[q] = beta[d0 + q] - s * mu;
        }
    } else {
#pragma unroll
        for (int q = 0; q < 8; q++) { sc[q] = 1.f; tt[q] = 0.f; }
    }
    int beg = rowstart[node];
    int end = rowstart[node + 1];
    float s0[8], s1[8], s2[8], s3[8];
#pragma unroll
    for (int q = 0; q < 8; q++) { s0[q] = 0.f; s1[q] = 0.f; s2[q] = 0.f; s3[q] = 0.f; }
    int j = beg;
    for (; j + 4 <= end; j += 4) {
        int sn0 = esrc[j], sn1 = esrc[j + 1], sn2 = esrc[j + 2], sn3 = esrc[j + 3];
        u16x8 v0 = *(const u16x8*)(X + (size_t)sn0 * DDIM + d0);
        u16x8 v1 = *(const u16x8*)(X + (size_t)sn1 * DDIM + d0);
        u16x8 v2 = *(const u16x8*)(X + (size_t)sn2 * DDIM + d0);
        u16x8 v3 = *(const u16x8*)(X + (size_t)sn3 * DDIM + d0);
#pragma unroll
        for (int q = 0; q < 8; q++) {
            s0[q] += bf2f(v0[q]);
            s1[q] += bf2f(v1[q]);
            s2[q] += bf2f(v2[q]);
            s3[q] += bf2f(v3[q]);
        }
    }
    for (; j < end; j++) {
        int sn0 = esrc[j];
        u16x8 v0 = *(const u16x8*)(X + (size_t)sn0 * DDIM + d0);
#pragma unroll
        for (int q = 0; q < 8; q++) s0[q] += bf2f(v0[q]);
    }
    float inv = (end > beg) ? 1.0f / (float)(end - beg) : 0.0f;
    float cnt = (end > beg) ? 2.0f : 1.0f;
    u16x8 xv = *(const u16x8*)(X + (size_t)node * DDIM + d0);
    u16x8 o;
#pragma unroll
    for (int q = 0; q < 8; q++) {
        float s = s0[q] + s1[q] + s2[q] + s3[q];
        o[q] = f2bf(sc[q] * (bf2f(xv[q]) + s * inv) + tt[q] * cnt);
    }
    *(u16x8*)(Hout + (size_t)node * DDIM + d0) = o;
}

// ---------------- bf16 MFMA GEMM (bn-folded m97 structure) ----------------
// C = relu(A @ W + bias). A[MPAD][256] bf16, Wt[n][k] bf16 (full 256 cols),
// C[MPAD][256] bf16. 128row x 256col tile, BK=32, 256 thr = 4 waves (2 row-
// halves x 2 col-halves), acc[4][8]. A staged ONCE (vs 2x in bn-split),
// 32 MFMA per wave per barrier pair. Epilogue in two col-halves via Ct.

__global__ __launch_bounds__(256) void k_gemm(const unsigned short* __restrict__ A,
                                              const unsigned short* __restrict__ Wt,
                                              const float* __restrict__ bias,
                                              unsigned short* __restrict__ C,
                                              float* __restrict__ part) {
    __shared__ unsigned short As[128 * 32];   // 8 KB
    __shared__ unsigned short Bs[256 * 32];   // 16 KB
    __shared__ unsigned short Ct[128 * 128];  // 32 KB
    __shared__ float sred[2][512];            // 4 KB

    const int tid = threadIdx.x;
    const int wv = tid >> 6;
    const int lane = tid & 63;
    const int bm = blockIdx.x;

    const int wr = (wv >> 1) * 64;   // row half
    const int wch = wv & 1;          // col half
    const int wc = wch * 128;
    const int lr = lane & 15;
    const int lk = lane >> 4;

    f32x4 acc[4][8];
#pragma unroll
    for (int m = 0; m < 4; m++)
#pragma unroll
        for (int n = 0; n < 8; n++) acc[m][n] = (f32x4)(0.f);

    for (int k0 = 0; k0 < 256; k0 += 32) {
        // A tile: 512 16B chunks
#pragma unroll
        for (int i = 0; i < 2; i++) {
            int c = wv * 128 + i * 64 + lane;
            int row = c >> 2;
            int kc = (c & 3) ^ ((row >> 1) & 3);  // inverse swizzle on source
            gld_lds16(A + (size_t)(bm * 128 + row) * 256 + k0 + kc * 8,
                      (void*)&As[(size_t)(wv * 128 + i * 64) * 8]);
        }
        // B tile (all 256 Wt rows): 1024 16B chunks
#pragma unroll
        for (int i = 0; i < 4; i++) {
            int c = wv * 256 + i * 64 + lane;
            int row = c >> 2;
            int kc = (c & 3) ^ ((row >> 1) & 3);
            gld_lds16(Wt + (size_t)row * 256 + k0 + kc * 8,
                      (void*)&Bs[(size_t)(wv * 256 + i * 64) * 8]);
        }
        __syncthreads();

        bf16x8 af[4], bfr[8];
#pragma unroll
        for (int m = 0; m < 4; m++) {
            int row = wr + m * 16 + lr;
            af[m] = ((const bf16x8*)As)[row * 4 + (lk ^ ((row >> 1) & 3))];
        }
#pragma unroll
        for (int n = 0; n < 8; n++) {
            int row = wc + n * 16 + lr;
            bfr[n] = ((const bf16x8*)Bs)[row * 4 + (lk ^ ((row >> 1) & 3))];
        }
#pragma unroll
        for (int m = 0; m < 4; m++)
#pragma unroll
            for (int n = 0; n < 8; n++)
                acc[m][n] = __builtin_amdgcn_mfma_f32_16x16x32_bf16(af[m], bfr[n],
                                                                    acc[m][n], 0, 0, 0);
        __syncthreads();
    }

    // ---- epilogue: two col-halves through Ct (32 KB) ----
    for (int h = 0; h < 2; h++) {
        if (wch == h) {
#pragma unroll
            for (int n = 0; n < 8; n++) {
                int cl = n * 16 + lr;            // col within 128-half
                int colg = h * 128 + cl;         // global col
                float bv = bias[colg];
                float sp = 0.f, ssp = 0.f;
#pragma unroll
                for (int m = 0; m < 4; m++)
#pragma unroll
                    for (int i = 0; i < 4; i++) {
                        int row = wr + m * 16 + lk * 4 + i;
                        float v = fmaxf(acc[m][n][i] + bv, 0.f);
                        Ct[row * 128 + (((cl >> 3) ^ (row & 7)) << 3) + (cl & 7)] =
                            f2bf(v);
                        if (bm * 128 + row < N_NODESC) { sp += v; ssp += v * v; }
                    }
                if (part) {
                    sp += __shfl_xor(sp, 16);
                    sp += __shfl_xor(sp, 32);
                    ssp += __shfl_xor(ssp, 16);
                    ssp += __shfl_xor(ssp, 32);
                    if (lane < 16) {
                        sred[wv >> 1][colg] = sp;
                        sred[wv >> 1][256 + colg] = ssp;
                    }
                }
            }
        }
        __syncthreads();
        // coalesced store of half h: 2048 16B chunks (16 chunks/row)
#pragma unroll
        for (int it = 0; it < 8; it++) {
            int chunk = it * 256 + tid;
            int row = chunk >> 4;
            int cc = chunk & 15;
            u16x8 v = *(const u16x8*)&Ct[row * 128 + ((cc ^ (row & 7)) << 3)];
            *(u16x8*)(C + (size_t)(bm * 128 + row) * DDIM + h * 128 + cc * 8) = v;
        }
        __syncthreads();
    }

    if (part) {
        part[(size_t)bm * 512 + tid] = sred[0][tid] + sred[1][tid];
        part[(size_t)bm * 512 + 256 + tid] = sred[0][256 + tid] + sred[1][256 + tid];
    }
}

// ---------------- stat partial reduction (2-stage, no atomics) ----------------

__global__ __launch_bounds__(512) void k_statred1(const float* __restrict__ part,
                                                  float* __restrict__ part2) {
    int t = threadIdx.x;
    int b0 = blockIdx.x * 17;
    float s = 0.f;
#pragma unroll 4
    for (int j = 0; j < 17; j++) s += part[(size_t)(b0 + j) * 512 + t];
    part2[(size_t)blockIdx.x * 512 + t] = s;
}

__global__ __launch_bounds__(512) void k_statred2(const float* __restrict__ part2,
                                                  float* __restrict__ stat) {
    int t = threadIdx.x;
    float s = 0.f;
#pragma unroll 4
    for (int j = 0; j < 23; j++) s += part2[(size_t)j * 512 + t];
    stat[t] = s;
}

// ---------------- classification head (applies final BN inline) ----------------

__global__ __launch_bounds__(256) void k_head(const unsigned short* __restrict__ Y,
                                              const int* __restrict__ counts,
                                              const float* __restrict__ stat,
                                              const float* __restrict__ gamma,
                                              const float* __restrict__ beta,
                                              const float* __restrict__ fcW1,
                                              const float* __restrict__ fcb1,
                                              const float* __restrict__ fcW2,
                                              const float* __restrict__ fcb2,
                                              float* __restrict__ out) {
    int g = blockIdx.x;
    __shared__ float row[DDIM];
    __shared__ float gv[DDIM];
    __shared__ float logits[NCLS];
    __shared__ int lastIdx;
    if (threadIdx.x == 0) {
        int s = 0;
        for (int i = 0; i <= g; i++) s += counts[i];
        lastIdx = s - 1;
    }
    __syncthreads();
    int j = threadIdx.x;
    const float invN = 1.0f / (float)N_NODESC;
    float mu = stat[j] * invN;
    float var = stat[256 + j] * invN - mu * mu;
    float sc = gamma[j] * rsqrtf(var + BN_EPSF);
    row[j] = sc * (bf2f(Y[(size_t)lastIdx * DDIM + j]) - mu) + beta[j];
    __syncthreads();
    float acc = fcb1[j];
    for (int d = 0; d < DDIM; d++) acc += row[d] * fcW1[(size_t)d * DDIM + j];
    gv[j] = fmaxf(acc, 0.f);
    __syncthreads();
    if (j < NCLS) {
        float a = fcb2[j];
        for (int d = 0; d < DDIM; d++) a += gv[d] * fcW2[(size_t)d * NCLS + j];
        logits[j] = a;
    }
    __syncthreads();
    if (j == 0) {
        float m = -1e30f;
        for (int c = 0; c < NCLS; c++) m = fmaxf(m, logits[c]);
        float se = 0.f;
        for (int c = 0; c < NCLS; c++) se += expf(logits[c] - m);
        float lse = m + logf(se);
        for (int c = 0; c < NCLS; c++) out[g * NCLS + c] = logits[c] - lse;
    }
}

// ---------------- launcher ----------------

extern "C" void kernel_launch(void* const* d_in, const int* in_sizes, int n_in,
                              void* d_out, int out_size, void* d_ws, size_t ws_size,
                              hipStream_t stream) {
    const float* x    = (const float*)d_in[0];
    const int* src    = (const int*)d_in[1];
    const int* dst    = (const int*)d_in[2];
    const int* counts = (const int*)d_in[3];
    const float* W1a  = (const float*)d_in[4];
    const float* b1a  = (const float*)d_in[5];
    const float* W1b  = (const float*)d_in[6];
    const float* b1b  = (const float*)d_in[7];
    const float* g1   = (const float*)d_in[8];
    const float* be1  = (const float*)d_in[9];
    const float* Ws1  = (const float*)d_in[10];
    const float* bs1  = (const float*)d_in[11];
    const float* Ws2  = (const float*)d_in[12];
    const float* bs2  = (const float*)d_in[13];
    const float* gms  = (const float*)d_in[14];
    const float* bts  = (const float*)d_in[15];
    const float* fcW1 = (const float*)d_in[16];
    const float* fcb1 = (const float*)d_in[17];
    const float* fcW2 = (const float*)d_in[18];
    const float* fcb2 = (const float*)d_in[19];
    float* out = (float*)d_out;

    char* ws = (char*)d_ws;
    const size_t BUF = (size_t)MPAD * DDIM * 2;  // 25,624,576 B
    unsigned short* B0 = (unsigned short*)(ws);
    unsigned short* B1 = (unsigned short*)(ws + BUF);
    unsigned short* B2 = (unsigned short*)(ws + 2 * BUF);
    unsigned short* Bx = (unsigned short*)(ws + 3 * BUF);          // 25.6 MB
    unsigned short* Wt = (unsigned short*)(ws + 4 * BUF);          // 1,310,720 B
    int* rowstart      = (int*)(ws + 4 * BUF + 1310720);           // 200,064 B
    int* cursor        = (int*)(ws + 4 * BUF + 1510784);           // 200,064 B
    int* esrc          = (int*)(ws + 4 * BUF + 1710848);           // 1,600,000 B
    float* stats       = (float*)(ws + 4 * BUF + 3310848);         // 10,240 B
    int* bsum          = (int*)(ws + 4 * BUF + 3321088);           // 784 B
    float* stats_part  = (float*)(ws + 4 * BUF + 3321872 + 16);    // 800,768 B
    float* stats_part2 = (float*)(ws + 4 * BUF + 4122656 + 32);    // 47,104 B

    // ---- CSR build ----
    k_zero32<<<dim3((N_NODESC + 255) / 256), 256, 0, stream>>>(cursor, N_NODESC);
    k_count<<<dim3((N_EDGESC + 255) / 256), 256, 0, stream>>>(dst, cursor);
    k_scan1<<<dim3(NBLK_SCAN), 256, 0, stream>>>(cursor, rowstart, bsum);
    k_scan2<<<dim3(NBLK_SCAN), 256, 0, stream>>>(rowstart, bsum);
    k_zero32<<<dim3((N_NODESC + 255) / 256), 256, 0, stream>>>(cursor, N_NODESC);
    k_fill<<<dim3((N_EDGESC + 255) / 256), 256, 0, stream>>>(src, dst, rowstart,
                                                             cursor, esrc);

    // ---- prep: weights, x->bf16 ----
    k_wprep<<<dim3((10 * 65536 + 255) / 256), 256, 0, stream>>>(W1a, W1b, Ws1, Ws2, Wt);
    k_xbf<<<dim3(12500), 256, 0, stream>>>(x, Bx);

    // ---- 5 GIN layers: agg (+prev BN) -> GEMM1 -> GEMM2 (+stat partials) ----
    for (int l = 0; l < 5; ++l) {
        const float* B1b = (l == 0) ? b1a : bs1 + (l - 1) * 256;
        const float* B2b = (l == 0) ? b1b : bs2 + (l - 1) * 256;
        const unsigned short* Wt1 = Wt + (size_t)(l * 2) * 65536;
        const unsigned short* Wt2 = Wt + (size_t)(l * 2 + 1) * 65536;

        if (l == 0) {
            k_agg_bf<<<dim3(6250), 256, 0, stream>>>(Bx, esrc, rowstart, nullptr,
                                                     nullptr, nullptr, B1);
        } else {
            const float* GA = (l == 1) ? g1 : gms + (l - 2) * 256;
            const float* BE = (l == 1) ? be1 : bts + (l - 2) * 256;
            k_agg_bf<<<dim3(6250), 256, 0, stream>>>(B0, esrc, rowstart,
                                                     stats + (size_t)(l - 1) * 512,
                                                     GA, BE, B1);
        }
        k_gemm<<<dim3(NBLK_GEMM), 256, 0, stream>>>(B1, Wt1, B1b, B2, nullptr);
        k_gemm<<<dim3(NBLK_GEMM), 256, 0, stream>>>(B2, Wt2, B2b, B0, stats_part);
        k_statred1<<<dim3(23), 512, 0, stream>>>(stats_part, stats_part2);
        k_statred2<<<dim3(1), 512, 0, stream>>>(stats_part2,
                                                stats + (size_t)l * 512);
    }

    // ---- head (applies layer-4 BN inline) ----
    k_head<<<dim3(N_GRAPHSC), 256, 0, stream>>>(B0, counts, stats + 4 * 512,
                                                gms + 3 * 256, bts + 3 * 256,
                                                fcW1, fcb1, fcW2, fcb2, out);
}

// Round 15
// 519.666 us; speedup vs baseline: 1.3616x; 1.3616x over previous
//
#include <hip/hip_runtime.h>
#include <hip/hip_bf16.h>

#define N_NODESC 50000
#define N_EDGESC 400000
#define N_GRAPHSC 250
#define DDIM 256
#define NCLS 10
#define BN_EPSF 1e-5f
#define MPAD 50048   // 391 * 128
#define NBLK_GEMM 391          // 17 * 23
#define NBLK_SCAN 196

typedef __attribute__((ext_vector_type(4))) float f32x4;
typedef __attribute__((ext_vector_type(8))) short bf16x8;
typedef __attribute__((ext_vector_type(8))) unsigned short u16x8;

__device__ __forceinline__ float bf2f(unsigned short h) {
    union { unsigned int u; float f; } c;
    c.u = ((unsigned int)h) << 16;
    return c.f;
}
__device__ __forceinline__ unsigned short f2bf(float f) {
    union { float f; unsigned int u; } c;
    c.f = f;
    unsigned int u = c.u;
    return (unsigned short)((u + 0x7FFFu + ((u >> 16) & 1u)) >> 16);
}

__device__ __forceinline__ void gld_lds16(const void* g, void* l) {
    __builtin_amdgcn_global_load_lds(
        (const __attribute__((address_space(1))) unsigned int*)g,
        (__attribute__((address_space(3))) unsigned int*)l, 16, 0, 0);
}

// ---------------- CSR build ----------------

__global__ void k_zero32(int* __restrict__ p, int n) {
    int i = blockIdx.x * blockDim.x + threadIdx.x;
    if (i < n) p[i] = 0;
}

__global__ void k_count(const int* __restrict__ dst, int* __restrict__ cnt) {
    int e = blockIdx.x * blockDim.x + threadIdx.x;
    if (e < N_EDGESC) atomicAdd(&cnt[dst[e]], 1);
}

__global__ __launch_bounds__(256) void k_scan1(const int* __restrict__ deg,
                                               int* __restrict__ rowstart,
                                               int* __restrict__ bsum) {
    __shared__ int sh[256];
    int tid = threadIdx.x;
    int i = blockIdx.x * 256 + tid;
    int v = (i < N_NODESC) ? deg[i] : 0;
    sh[tid] = v;
    __syncthreads();
    for (int off = 1; off < 256; off <<= 1) {
        int t = (tid >= off) ? sh[tid - off] : 0;
        __syncthreads();
        sh[tid] += t;
        __syncthreads();
    }
    if (i < N_NODESC) rowstart[i] = sh[tid] - v;
    if (tid == 255) bsum[blockIdx.x] = sh[255];
}

__global__ __launch_bounds__(256) void k_scan2(int* __restrict__ rowstart,
                                               const int* __restrict__ bsum) {
    __shared__ int sh[256];
    int tid = threadIdx.x;
    sh[tid] = (tid < NBLK_SCAN) ? bsum[tid] : 0;
    __syncthreads();
    for (int off = 1; off < 256; off <<= 1) {
        int t = (tid >= off) ? sh[tid - off] : 0;
        __syncthreads();
        sh[tid] += t;
        __syncthreads();
    }
    int i = blockIdx.x * 256 + tid;
    if (blockIdx.x > 0 && i < N_NODESC) rowstart[i] += sh[blockIdx.x - 1];
    if (i == 0) rowstart[N_NODESC] = N_EDGESC;
}

__global__ void k_fill(const int* __restrict__ src, const int* __restrict__ dst,
                       const int* __restrict__ rowstart, int* __restrict__ cur,
                       int* __restrict__ esrc) {
    int e = blockIdx.x * blockDim.x + threadIdx.x;
    if (e < N_EDGESC) {
        int d = dst[e];
        int pos = rowstart[d] + atomicAdd(&cur[d], 1);
        esrc[pos] = src[e];
    }
}

// ---------------- weight prep: W[k][n] f32 -> Wt[n][k] bf16, 10 matrices ----------------

__global__ __launch_bounds__(256) void k_wprep(const float* __restrict__ W1a,
                                               const float* __restrict__ W1b,
                                               const float* __restrict__ Ws1,
                                               const float* __restrict__ Ws2,
                                               unsigned short* __restrict__ Wt) {
    int i = blockIdx.x * blockDim.x + threadIdx.x;
    if (i >= 10 * 65536) return;
    int m = i >> 16;
    int r = i & 65535;
    int n = r >> 8;
    int k = r & 255;
    int l = m >> 1, wsel = m & 1;
    const float* src = (l == 0) ? (wsel ? W1b : W1a)
                                : (wsel ? Ws2 + (size_t)(l - 1) * 65536
                                        : Ws1 + (size_t)(l - 1) * 65536);
    Wt[i] = f2bf(src[(size_t)k * 256 + n]);
}

// x fp32 -> bf16
__global__ __launch_bounds__(256) void k_xbf(const float* __restrict__ X,
                                             unsigned short* __restrict__ Y) {
    int i = blockIdx.x * 256 + threadIdx.x;
    if (i < N_NODESC * 64) {
        float4 v = ((const float4*)X)[i];
        ushort4 o;
        o.x = f2bf(v.x); o.y = f2bf(v.y); o.z = f2bf(v.z); o.w = f2bf(v.w);
        ((ushort4*)Y)[i] = o;
    }
}

// ---------------- mean aggregation + (optional) previous layer's BN ----------------
// BN affine commutes with mean-agg: out = sc*(x + mean_src) + tt*(deg>0?2:1).
// One node per half-wave (32 lanes x 16B = 512B row), unroll x4.

__global__ __launch_bounds__(256) void k_agg_bf(const unsigned short* __restrict__ X,
                                                const int* __restrict__ esrc,
                                                const int* __restrict__ rowstart,
                                                const float* __restrict__ stat,
                                                const float* __restrict__ gamma,
                                                const float* __restrict__ beta,
                                                unsigned short* __restrict__ Hout) {
    int node = blockIdx.x * 8 + (threadIdx.x >> 5);
    if (node >= N_NODESC) return;
    int lane = threadIdx.x & 31;
    int d0 = lane * 8;
    float sc[8], tt[8];
    if (stat) {
        const float invN = 1.0f / (float)N_NODESC;
#pragma unroll
        for (int q = 0; q < 8; q++) {
            float mu = stat[d0 + q] * invN;
            float var = stat[256 + d0 + q] * invN - mu * mu;
            float s = gamma[d0 + q] * rsqrtf(var + BN_EPSF);
            sc[q] = s;
            tt[q] = beta[d0 + q] - s * mu;
        }
    } else {
#pragma unroll
        for (int q = 0; q < 8; q++) { sc[q] = 1.f; tt[q] = 0.f; }
    }
    int beg = rowstart[node];
    int end = rowstart[node + 1];
    float s0[8], s1[8], s2[8], s3[8];
#pragma unroll
    for (int q = 0; q < 8; q++) { s0[q] = 0.f; s1[q] = 0.f; s2[q] = 0.f; s3[q] = 0.f; }
    int j = beg;
    for (; j + 4 <= end; j += 4) {
        int sn0 = esrc[j], sn1 = esrc[j + 1], sn2 = esrc[j + 2], sn3 = esrc[j + 3];
        u16x8 v0 = *(const u16x8*)(X + (size_t)sn0 * DDIM + d0);
        u16x8 v1 = *(const u16x8*)(X + (size_t)sn1 * DDIM + d0);
        u16x8 v2 = *(const u16x8*)(X + (size_t)sn2 * DDIM + d0);
        u16x8 v3 = *(const u16x8*)(X + (size_t)sn3 * DDIM + d0);
#pragma unroll
        for (int q = 0; q < 8; q++) {
            s0[q] += bf2f(v0[q]);
            s1[q] += bf2f(v1[q]);
            s2[q] += bf2f(v2[q]);
            s3[q] += bf2f(v3[q]);
        }
    }
    for (; j < end; j++) {
        int sn0 = esrc[j];
        u16x8 v0 = *(const u16x8*)(X + (size_t)sn0 * DDIM + d0);
#pragma unroll
        for (int q = 0; q < 8; q++) s0[q] += bf2f(v0[q]);
    }
    float inv = (end > beg) ? 1.0f / (float)(end - beg) : 0.0f;
    float cnt = (end > beg) ? 2.0f : 1.0f;
    u16x8 xv = *(const u16x8*)(X + (size_t)node * DDIM + d0);
    u16x8 o;
#pragma unroll
    for (int q = 0; q < 8; q++) {
        float s = s0[q] + s1[q] + s2[q] + s3[q];
        o[q] = f2bf(sc[q] * (bf2f(xv[q]) + s * inv) + tt[q] * cnt);
    }
    *(u16x8*)(Hout + (size_t)node * DDIM + d0) = o;
}

// ---------------- bf16 MFMA GEMM (m97 structure, BK=64) ----------------
// C = relu(A @ W + bias). A[MPAD][256] bf16, Wt[n][k] bf16, C[MPAD][256] bf16.
// 128x128 tile, BK=64 (4 barrier pairs, 32 MFMA/wave each), 256 thr = 4 waves
// (2x2), acc[4][4] (64 VGPR - no register cliff). global_load_lds staging,
// 8-slot XOR chunk swizzle (slot = g ^ (row&7), same involution both sides).
// Epilogue restaged through Ct for coalesced 16B stores; LDS col-stat
// partials (no atomics).

__global__ __launch_bounds__(256) void k_gemm(const unsigned short* __restrict__ A,
                                              const unsigned short* __restrict__ Wt,
                                              const float* __restrict__ bias,
                                              unsigned short* __restrict__ C,
                                              float* __restrict__ part) {
    __shared__ unsigned short As[128 * 64];   // 16 KB
    __shared__ unsigned short Bs[128 * 64];   // 16 KB
    __shared__ unsigned short Ct[128 * 128];  // 32 KB
    __shared__ float sred[2][256];            // 2 KB

    const int tid = threadIdx.x;
    const int wv = tid >> 6;
    const int lane = tid & 63;
    const int bm = blockIdx.x;
    const int bn = blockIdx.y;

    const int wr = (wv >> 1) * 64;
    const int wc = (wv & 1) * 64;
    const int lr = lane & 15;
    const int lk = lane >> 4;

    f32x4 acc[4][4];
#pragma unroll
    for (int m = 0; m < 4; m++)
#pragma unroll
        for (int n = 0; n < 4; n++) acc[m][n] = (f32x4)(0.f);

    for (int k0 = 0; k0 < 256; k0 += 64) {
        // A+B tiles: 1024 16B-chunks each (8 chunks/row of 64 bf16), 4/thread
#pragma unroll
        for (int i = 0; i < 4; i++) {
            int c = wv * 256 + i * 64 + lane;
            int row = c >> 3;
            int kc = (c & 7) ^ (row & 7);  // inverse swizzle on source
            gld_lds16(A + (size_t)(bm * 128 + row) * 256 + k0 + kc * 8,
                      (void*)&As[(size_t)c * 8]);
            gld_lds16(Wt + (size_t)(bn * 128 + row) * 256 + k0 + kc * 8,
                      (void*)&Bs[(size_t)c * 8]);
        }
        __syncthreads();

#pragma unroll
        for (int ks = 0; ks < 2; ks++) {
            bf16x8 af[4], bfr[4];
#pragma unroll
            for (int m = 0; m < 4; m++) {
                int row = wr + m * 16 + lr;
                af[m] = ((const bf16x8*)As)[row * 8 + ((ks * 4 + lk) ^ (row & 7))];
            }
#pragma unroll
            for (int n = 0; n < 4; n++) {
                int row = wc + n * 16 + lr;
                bfr[n] = ((const bf16x8*)Bs)[row * 8 + ((ks * 4 + lk) ^ (row & 7))];
            }
#pragma unroll
            for (int m = 0; m < 4; m++)
#pragma unroll
                for (int n = 0; n < 4; n++)
                    acc[m][n] = __builtin_amdgcn_mfma_f32_16x16x32_bf16(
                        af[m], bfr[n], acc[m][n], 0, 0, 0);
        }
        __syncthreads();
    }

    // ---- epilogue: bias+relu -> Ct (swizzled), optional stats to sred ----
#pragma unroll
    for (int n = 0; n < 4; n++) {
        int cloc = wc + n * 16 + lr;                 // col within 128-block
        float bv = bias[bn * 128 + cloc];
        float sp = 0.f, ssp = 0.f;
#pragma unroll
        for (int m = 0; m < 4; m++)
#pragma unroll
            for (int i = 0; i < 4; i++) {
                int row = wr + m * 16 + lk * 4 + i;
                float v = fmaxf(acc[m][n][i] + bv, 0.f);
                Ct[row * 128 + (((cloc >> 3) ^ (row & 7)) << 3) + (cloc & 7)] = f2bf(v);
                if (bm * 128 + row < N_NODESC) { sp += v; ssp += v * v; }
            }
        if (part) {
            sp += __shfl_xor(sp, 16);
            sp += __shfl_xor(sp, 32);
            ssp += __shfl_xor(ssp, 16);
            ssp += __shfl_xor(ssp, 32);
            if (lane < 16) {
                sred[wv >> 1][cloc] = sp;
                sred[wv >> 1][128 + cloc] = ssp;
            }
        }
    }
    __syncthreads();

    // ---- coalesced C store: 2048 16B chunks (16 chunks/row of 128 cols) ----
#pragma unroll
    for (int it = 0; it < 8; it++) {
        int chunk = it * 256 + tid;
        int row = chunk >> 4;
        int cc = chunk & 15;
        u16x8 v = *(const u16x8*)&Ct[row * 128 + ((cc ^ (row & 7)) << 3)];
        *(u16x8*)(C + (size_t)(bm * 128 + row) * DDIM + bn * 128 + cc * 8) = v;
    }
    if (part && tid < 256) {
        float v = sred[0][tid] + sred[1][tid];
        int cloc = tid & 127;
        int off = (tid < 128) ? (bn * 128 + cloc) : (256 + bn * 128 + cloc);
        part[(size_t)bm * 512 + off] = v;
    }
}

// ---------------- stat partial reduction (2-stage, no atomics) ----------------

__global__ __launch_bounds__(512) void k_statred1(const float* __restrict__ part,
                                                  float* __restrict__ part2) {
    int t = threadIdx.x;
    int b0 = blockIdx.x * 17;
    float s = 0.f;
#pragma unroll 4
    for (int j = 0; j < 17; j++) s += part[(size_t)(b0 + j) * 512 + t];
    part2[(size_t)blockIdx.x * 512 + t] = s;
}

__global__ __launch_bounds__(512) void k_statred2(const float* __restrict__ part2,
                                                  float* __restrict__ stat) {
    int t = threadIdx.x;
    float s = 0.f;
#pragma unroll 4
    for (int j = 0; j < 23; j++) s += part2[(size_t)j * 512 + t];
    stat[t] = s;
}

// ---------------- classification head (applies final BN inline) ----------------

__global__ __launch_bounds__(256) void k_head(const unsigned short* __restrict__ Y,
                                              const int* __restrict__ counts,
                                              const float* __restrict__ stat,
                                              const float* __restrict__ gamma,
                                              const float* __restrict__ beta,
                                              const float* __restrict__ fcW1,
                                              const float* __restrict__ fcb1,
                                              const float* __restrict__ fcW2,
                                              const float* __restrict__ fcb2,
                                              float* __restrict__ out) {
    int g = blockIdx.x;
    __shared__ float row[DDIM];
    __shared__ float gv[DDIM];
    __shared__ float logits[NCLS];
    __shared__ int lastIdx;
    if (threadIdx.x == 0) {
        int s = 0;
        for (int i = 0; i <= g; i++) s += counts[i];
        lastIdx = s - 1;
    }
    __syncthreads();
    int j = threadIdx.x;
    const float invN = 1.0f / (float)N_NODESC;
    float mu = stat[j] * invN;
    float var = stat[256 + j] * invN - mu * mu;
    float sc = gamma[j] * rsqrtf(var + BN_EPSF);
    row[j] = sc * (bf2f(Y[(size_t)lastIdx * DDIM + j]) - mu) + beta[j];
    __syncthreads();
    float acc = fcb1[j];
    for (int d = 0; d < DDIM; d++) acc += row[d] * fcW1[(size_t)d * DDIM + j];
    gv[j] = fmaxf(acc, 0.f);
    __syncthreads();
    if (j < NCLS) {
        float a = fcb2[j];
        for (int d = 0; d < DDIM; d++) a += gv[d] * fcW2[(size_t)d * NCLS + j];
        logits[j] = a;
    }
    __syncthreads();
    if (j == 0) {
        float m = -1e30f;
        for (int c = 0; c < NCLS; c++) m = fmaxf(m, logits[c]);
        float se = 0.f;
        for (int c = 0; c < NCLS; c++) se += expf(logits[c] - m);
        float lse = m + logf(se);
        for (int c = 0; c < NCLS; c++) out[g * NCLS + c] = logits[c] - lse;
    }
}

// ---------------- launcher ----------------

extern "C" void kernel_launch(void* const* d_in, const int* in_sizes, int n_in,
                              void* d_out, int out_size, void* d_ws, size_t ws_size,
                              hipStream_t stream) {
    const float* x    = (const float*)d_in[0];
    const int* src    = (const int*)d_in[1];
    const int* dst    = (const int*)d_in[2];
    const int* counts = (const int*)d_in[3];
    const float* W1a  = (const float*)d_in[4];
    const float* b1a  = (const float*)d_in[5];
    const float* W1b  = (const float*)d_in[6];
    const float* b1b  = (const float*)d_in[7];
    const float* g1   = (const float*)d_in[8];
    const float* be1  = (const float*)d_in[9];
    const float* Ws1  = (const float*)d_in[10];
    const float* bs1  = (const float*)d_in[11];
    const float* Ws2  = (const float*)d_in[12];
    const float* bs2  = (const float*)d_in[13];
    const float* gms  = (const float*)d_in[14];
    const float* bts  = (const float*)d_in[15];
    const float* fcW1 = (const float*)d_in[16];
    const float* fcb1 = (const float*)d_in[17];
    const float* fcW2 = (const float*)d_in[18];
    const float* fcb2 = (const float*)d_in[19];
    float* out = (float*)d_out;

    char* ws = (char*)d_ws;
    const size_t BUF = (size_t)MPAD * DDIM * 2;  // 25,624,576 B
    unsigned short* B0 = (unsigned short*)(ws);
    unsigned short* B1 = (unsigned short*)(ws + BUF);
    unsigned short* B2 = (unsigned short*)(ws + 2 * BUF);
    unsigned short* Bx = (unsigned short*)(ws + 3 * BUF);          // 25.6 MB
    unsigned short* Wt = (unsigned short*)(ws + 4 * BUF);          // 1,310,720 B
    int* rowstart      = (int*)(ws + 4 * BUF + 1310720);           // 200,064 B
    int* cursor        = (int*)(ws + 4 * BUF + 1510784);           // 200,064 B
    int* esrc          = (int*)(ws + 4 * BUF + 1710848);           // 1,600,000 B
    float* stats       = (float*)(ws + 4 * BUF + 3310848);         // 10,240 B
    int* bsum          = (int*)(ws + 4 * BUF + 3321088);           // 784 B
    float* stats_part  = (float*)(ws + 4 * BUF + 3321872 + 16);    // 800,768 B
    float* stats_part2 = (float*)(ws + 4 * BUF + 4122656 + 32);    // 47,104 B

    // ---- CSR build ----
    k_zero32<<<dim3((N_NODESC + 255) / 256), 256, 0, stream>>>(cursor, N_NODESC);
    k_count<<<dim3((N_EDGESC + 255) / 256), 256, 0, stream>>>(dst, cursor);
    k_scan1<<<dim3(NBLK_SCAN), 256, 0, stream>>>(cursor, rowstart, bsum);
    k_scan2<<<dim3(NBLK_SCAN), 256, 0, stream>>>(rowstart, bsum);
    k_zero32<<<dim3((N_NODESC + 255) / 256), 256, 0, stream>>>(cursor, N_NODESC);
    k_fill<<<dim3((N_EDGESC + 255) / 256), 256, 0, stream>>>(src, dst, rowstart,
                                                             cursor, esrc);

    // ---- prep: weights, x->bf16 ----
    k_wprep<<<dim3((10 * 65536 + 255) / 256), 256, 0, stream>>>(W1a, W1b, Ws1, Ws2, Wt);
    k_xbf<<<dim3(12500), 256, 0, stream>>>(x, Bx);

    // ---- 5 GIN layers: agg (+prev BN) -> GEMM1 -> GEMM2 (+stat partials) ----
    for (int l = 0; l < 5; ++l) {
        const float* B1b = (l == 0) ? b1a : bs1 + (l - 1) * 256;
        const float* B2b = (l == 0) ? b1b : bs2 + (l - 1) * 256;
        const unsigned short* Wt1 = Wt + (size_t)(l * 2) * 65536;
        const unsigned short* Wt2 = Wt + (size_t)(l * 2 + 1) * 65536;

        if (l == 0) {
            k_agg_bf<<<dim3(6250), 256, 0, stream>>>(Bx, esrc, rowstart, nullptr,
                                                     nullptr, nullptr, B1);
        } else {
            const float* GA = (l == 1) ? g1 : gms + (l - 2) * 256;
            const float* BE = (l == 1) ? be1 : bts + (l - 2) * 256;
            k_agg_bf<<<dim3(6250), 256, 0, stream>>>(B0, esrc, rowstart,
                                                     stats + (size_t)(l - 1) * 512,
                                                     GA, BE, B1);
        }
        k_gemm<<<dim3(NBLK_GEMM, 2), 256, 0, stream>>>(B1, Wt1, B1b, B2, nullptr);
        k_gemm<<<dim3(NBLK_GEMM, 2), 256, 0, stream>>>(B2, Wt2, B2b, B0, stats_part);
        k_statred1<<<dim3(23), 512, 0, stream>>>(stats_part, stats_part2);
        k_statred2<<<dim3(1), 512, 0, stream>>>(stats_part2,
                                                stats + (size_t)l * 512);
    }

    // ---- head (applies layer-4 BN inline) ----
    k_head<<<dim3(N_GRAPHSC), 256, 0, stream>>>(B0, counts, stats + 4 * 512,
                                                gms + 3 * 256, bts + 3 * 256,
                                                fcW1, fcb1, fcW2, fcb2, out);
}